// Round 5
// baseline (19633.702 us; speedup 1.0000x reference)
//
#include <hip/hip_runtime.h>
#include <hip/hip_bf16.h>

using u16 = unsigned short;
using u32 = unsigned int;

constexpr int Bn = 4;
constexpr int Cn = 384;
constexpr int Hn = 128;
constexpr int Wn = 128;
constexpr int Nn = Hn * Wn;        // 16384
constexpr int HEADS_ = 8;
constexpr int CH = Cn / HEADS_;    // 48

// ---- bf16 <-> f32 helpers (RNE, matches np/jax cast) ----
__device__ __forceinline__ float bf2f(u16 u) {
    u32 w = ((u32)u) << 16;
    return __builtin_bit_cast(float, w);
}
__device__ __forceinline__ u16 f2bf(float f) {
    u32 x = __builtin_bit_cast(u32, f);
    u32 r = (x + 0x7FFFu + ((x >> 16) & 1u)) >> 16;   // round-nearest-even
    return (u16)r;
}

// ---------------- LayerNorm over channel dim; out bf16 ----------------
// INMODE 0: fp32 input, 1: bf16 input
template<int INMODE>
__global__ __launch_bounds__(256) void ln_kernel(
    const void* __restrict__ xv, const float* __restrict__ w,
    const float* __restrict__ bias, u16* __restrict__ out)
{
    int n = blockIdx.x * 256 + threadIdx.x;
    int b = blockIdx.y;
    size_t base = (size_t)b * Cn * Nn + n;
    const float* pxf = (const float*)xv + base;
    const u16*   pxh = (const u16*)xv + base;
    u16* po = out + base;
    float sum = 0.f, sumsq = 0.f;
    for (int c = 0; c < Cn; ++c) {
        float v = (INMODE == 1) ? bf2f(pxh[(size_t)c * Nn]) : pxf[(size_t)c * Nn];
        sum += v; sumsq += v * v;
    }
    float mu = sum * (1.0f / Cn);
    float var = sumsq * (1.0f / Cn) - mu * mu;
    float rs = rsqrtf(var + 1e-5f);
    for (int c = 0; c < Cn; ++c) {
        float v = (INMODE == 1) ? bf2f(pxh[(size_t)c * Nn]) : pxf[(size_t)c * Nn];
        po[(size_t)c * Nn] = f2bf((v - mu) * rs * w[c] + bias[c]);
    }
}

// ---------------- depthwise 3x3, SAME, bf16 in/out, 384 ch ----------------
__device__ __forceinline__ float gelu_exact(float v) {
    return 0.5f * v * (1.f + erff(v * 0.7071067811865475f));
}

// MODE 0: out = dw(in); 1: out = gelu(dw(in)); 2: out *= dw(in)
template<int MODE>
__global__ __launch_bounds__(256) void dwconv_kernel(
    const u16* __restrict__ in, const float* __restrict__ wdw,
    u16* out)
{
    int n = blockIdx.x * 256 + threadIdx.x;
    int c = blockIdx.y;
    int b = blockIdx.z;
    int h = n >> 7, w = n & (Wn - 1);
    const u16* pi = in + ((size_t)b * Cn + c) * Nn;
    const float* pw = wdw + c * 9;
    float acc = 0.f;
    #pragma unroll
    for (int ky = 0; ky < 3; ++ky) {
        int hh = h + ky - 1;
        if (hh < 0 || hh >= Hn) continue;
        #pragma unroll
        for (int kx = 0; kx < 3; ++kx) {
            int ww = w + kx - 1;
            if (ww < 0 || ww >= Wn) continue;
            acc = fmaf(bf2f(pi[hh * Wn + ww]), pw[ky * 3 + kx], acc);
        }
    }
    size_t oidx = ((size_t)b * Cn + c) * Nn + n;
    if (MODE == 0)      out[oidx] = f2bf(acc);
    else if (MODE == 1) out[oidx] = f2bf(gelu_exact(acc));
    else                out[oidx] = f2bf(bf2f(out[oidx]) * acc);
}

// ---- simple GEMM: Out[b,o,n] = sum_c W[o,c]*X[b,c,n] (+res); O=384 ----
// block 256 = 64 lanes(n) x 4 o-groups; thread computes 4 o's.
// RESMODE 0: none (bf16 out), 1: fp32 residual + fp32 out
template<int RESMODE>
__global__ __launch_bounds__(256) void sgemm(
    const float* __restrict__ W, const u16* __restrict__ X,
    const float* __restrict__ resf, void* __restrict__ Outv, int K)
{
    int lane = threadIdx.x & 63;
    int og   = threadIdx.x >> 6;              // 0..3
    int n    = blockIdx.x * 64 + lane;
    int o0   = blockIdx.y * 16 + og * 4;
    int b    = blockIdx.z;
    const u16* Xb = X + (size_t)b * K * Nn + n;
    const float* w0 = W + (size_t)(o0 + 0) * K;
    const float* w1 = W + (size_t)(o0 + 1) * K;
    const float* w2 = W + (size_t)(o0 + 2) * K;
    const float* w3 = W + (size_t)(o0 + 3) * K;
    float a0 = 0.f, a1 = 0.f, a2 = 0.f, a3 = 0.f;
    #pragma unroll 8
    for (int c = 0; c < K; ++c) {
        float xv = bf2f(Xb[(size_t)c * Nn]);
        a0 = fmaf(w0[c], xv, a0);
        a1 = fmaf(w1[c], xv, a1);
        a2 = fmaf(w2[c], xv, a2);
        a3 = fmaf(w3[c], xv, a3);
    }
    size_t i0 = ((size_t)b * 384 + o0) * Nn + n;
    if (RESMODE == 1) {
        float* Out = (float*)Outv;
        Out[i0]                  = a0 + resf[i0];
        Out[i0 + (size_t)Nn]     = a1 + resf[i0 + (size_t)Nn];
        Out[i0 + (size_t)2 * Nn] = a2 + resf[i0 + (size_t)2 * Nn];
        Out[i0 + (size_t)3 * Nn] = a3 + resf[i0 + (size_t)3 * Nn];
    } else {
        u16* Out = (u16*)Outv;
        Out[i0]                  = f2bf(a0);
        Out[i0 + (size_t)Nn]     = f2bf(a1);
        Out[i0 + (size_t)2 * Nn] = f2bf(a2);
        Out[i0 + (size_t)3 * Nn] = f2bf(a3);
    }
}

// ---- final FFN GEMM: Out = Out + W2 @ [h1a; h1b], K=768, O=384 ----
// Out is fp32 (d_out), in-place residual: each thread reads only its own
// 4 elements then overwrites them.
__global__ __launch_bounds__(256) void sgemm_ffn(
    const float* __restrict__ W, const u16* __restrict__ Xa,
    const u16* __restrict__ Xb2, float* Out)
{
    int lane = threadIdx.x & 63;
    int og   = threadIdx.x >> 6;
    int n    = blockIdx.x * 64 + lane;
    int o0   = blockIdx.y * 16 + og * 4;
    int b    = blockIdx.z;
    const u16* Pa = Xa  + (size_t)b * 384 * Nn + n;
    const u16* Pb = Xb2 + (size_t)b * 384 * Nn + n;
    const float* w0 = W + (size_t)(o0 + 0) * 768;
    const float* w1 = W + (size_t)(o0 + 1) * 768;
    const float* w2 = W + (size_t)(o0 + 2) * 768;
    const float* w3 = W + (size_t)(o0 + 3) * 768;
    float a0 = 0.f, a1 = 0.f, a2 = 0.f, a3 = 0.f;
    #pragma unroll 8
    for (int c = 0; c < 384; ++c) {
        float xv = bf2f(Pa[(size_t)c * Nn]);
        a0 = fmaf(w0[c], xv, a0);
        a1 = fmaf(w1[c], xv, a1);
        a2 = fmaf(w2[c], xv, a2);
        a3 = fmaf(w3[c], xv, a3);
    }
    #pragma unroll 8
    for (int c = 0; c < 384; ++c) {
        float xv = bf2f(Pb[(size_t)c * Nn]);
        a0 = fmaf(w0[384 + c], xv, a0);
        a1 = fmaf(w1[384 + c], xv, a1);
        a2 = fmaf(w2[384 + c], xv, a2);
        a3 = fmaf(w3[384 + c], xv, a3);
    }
    size_t i0 = ((size_t)b * 384 + o0) * Nn + n;
    Out[i0]                  += a0;
    Out[i0 + (size_t)Nn]     += a1;
    Out[i0 + (size_t)2 * Nn] += a2;
    Out[i0 + (size_t)3 * Nn] += a3;
}

// ---------------- row sum-of-squares -> rsqrt factor (bf16 input) ----------------
__global__ __launch_bounds__(256) void rowsumsq_kernel(
    const u16* __restrict__ t, float* __restrict__ rsq)
{
    int row = blockIdx.x;                   // b*Cn + c
    const u16* p = t + (size_t)row * Nn;
    int tid = threadIdx.x;
    float s = 0.f;
    for (int i = tid; i < Nn; i += 256) {
        float v = bf2f(p[i]);
        s = fmaf(v, v, s);
    }
    #pragma unroll
    for (int off = 32; off > 0; off >>= 1) s += __shfl_xor(s, off);
    __shared__ float red[4];
    if ((tid & 63) == 0) red[tid >> 6] = s;
    __syncthreads();
    if (tid == 0) rsq[row] = rsqrtf(red[0] + red[1] + red[2] + red[3] + 1e-12f);
}

// ---------------- QK^T raw dots: wave per (c,d) pair subset ----------------
__global__ __launch_bounds__(256) void qk_simple(
    const u16* __restrict__ q, const u16* __restrict__ k,
    float* __restrict__ attn)
{
    int lane = threadIdx.x & 63, wv = threadIdx.x >> 6;
    int cb = blockIdx.x * 6;                // 8 blocks x 6 c's = 48
    int h = blockIdx.y, b = blockIdx.z;
    const u16* qb = q + ((size_t)b * Cn + h * CH) * Nn;
    const u16* kb = k + ((size_t)b * Cn + h * CH) * Nn;
    float* ap = attn + (size_t)(b * HEADS_ + h) * CH * CH;
    for (int p = wv; p < 6 * CH; p += 4) {
        int c = cb + p / CH, d = p % CH;
        const u16* qr = qb + (size_t)c * Nn;
        const u16* kr = kb + (size_t)d * Nn;
        float s = 0.f;
        for (int i = lane; i < Nn; i += 64)
            s = fmaf(bf2f(qr[i]), bf2f(kr[i]), s);
        #pragma unroll
        for (int off = 32; off > 0; off >>= 1) s += __shfl_xor(s, off);
        if (lane == 0) ap[c * CH + d] = s;
    }
}

// ---------------- softmax over d (48) with temp & L2-norm factors ----------------
__global__ void softmax_kernel(float* __restrict__ attn,
                               const float* __restrict__ temp,
                               const float* __restrict__ rq,
                               const float* __restrict__ rk)
{
    int row = blockIdx.x;                   // B*H*CH rows
    int c = row % CH;
    int bh = row / CH;
    int h = bh % HEADS_, b = bh / HEADS_;
    float* p = attn + (size_t)row * CH;
    int d = threadIdx.x;                    // 64 lanes
    float tv = temp[h] * rq[b * Cn + h * CH + c];
    float raw = 0.f, val = -3.402823466e38f;
    if (d < CH) { raw = p[d] * tv * rk[b * Cn + h * CH + d]; val = raw; }
    #pragma unroll
    for (int off = 32; off > 0; off >>= 1) val = fmaxf(val, __shfl_xor(val, off));
    float e = (d < CH) ? __expf(raw - val) : 0.f;
    float s = e;
    #pragma unroll
    for (int off = 32; off > 0; off >>= 1) s += __shfl_xor(s, off);
    if (d < CH) p[d] = e / s;
}

// ---------------- PV: out[b,h*CH+c,n] = sum_d attn[c,d]*v[d,n] ----------------
__global__ __launch_bounds__(256) void pv_simple(
    const float* __restrict__ attn, const u16* __restrict__ v,
    u16* __restrict__ out)
{
    int t = threadIdx.x;
    int n = blockIdx.x * 256 + t;
    int h = blockIdx.y, b = blockIdx.z;
    const u16* vb = v + ((size_t)b * Cn + h * CH) * Nn + n;
    const float* ap = attn + (size_t)(b * HEADS_ + h) * CH * CH;
    u16* ob = out + ((size_t)b * Cn + h * CH) * Nn + n;
    for (int c = 0; c < CH; ++c) {
        float s = 0.f;
        #pragma unroll 8
        for (int d = 0; d < CH; ++d)
            s = fmaf(ap[c * CH + d], bf2f(vb[(size_t)d * Nn]), s);
        ob[(size_t)c * Nn] = f2bf(s);
    }
}

extern "C" void kernel_launch(void* const* d_in, const int* in_sizes, int n_in,
                              void* d_out, int out_size, void* d_ws, size_t ws_size,
                              hipStream_t stream) {
    const float* x        = (const float*)d_in[0];
    const float* y        = (const float*)d_in[1];
    const float* n1_w     = (const float*)d_in[2];
    const float* n1_b     = (const float*)d_in[3];
    const float* n1y_w    = (const float*)d_in[4];
    const float* n1y_b    = (const float*)d_in[5];
    const float* q_w      = (const float*)d_in[6];
    const float* q_dw     = (const float*)d_in[7];
    const float* kv_w     = (const float*)d_in[8];
    const float* kv_dw    = (const float*)d_in[9];
    const float* temp     = (const float*)d_in[10];
    const float* proj_w   = (const float*)d_in[11];
    const float* n2_w     = (const float*)d_in[12];
    const float* n2_b     = (const float*)d_in[13];
    const float* ffn_in_w = (const float*)d_in[14];
    const float* ffn_dw   = (const float*)d_in[15];
    const float* ffn_out_w= (const float*)d_in[16];
    float* outp = (float*)d_out;             // OUTPUT IS FP32

    const size_t S = (size_t)Bn * Cn * Nn;   // 25,165,824 elems (one 384-ch tensor)

    // ws: 4 bf16 S-buffers (192MB) + fp32 smalls (~0.4MB). Total < 193MB.
    u16* A = (u16*)d_ws;
    u16* B = A + S;
    u16* C = B + S;
    u16* D = C + S;
    float* rq   = (float*)(D + S);
    float* rk   = rq + Bn * Cn;
    float* attn = rk + Bn * Cn;      // Bn*HEADS_*CH*CH = 92160 floats

    dim3 blk(256);
    dim3 gLN(Nn / 256, Bn);
    dim3 gDW(Nn / 256, Cn, Bn);
    dim3 gGE(Nn / 64, 384 / 16, Bn);

    // --- attention branch ---
    ln_kernel<0><<<gLN, blk, 0, stream>>>(x, n1_w, n1_b, A);                 // xn -> A
    sgemm<0><<<gGE, blk, 0, stream>>>(q_w, A, nullptr, B, 384);              // qpre -> B
    dwconv_kernel<0><<<gDW, blk, 0, stream>>>(B, q_dw, C);                   // q -> C

    ln_kernel<0><<<gLN, blk, 0, stream>>>(y, n1y_w, n1y_b, A);               // yn -> A
    sgemm<0><<<gGE, blk, 0, stream>>>(kv_w, A, nullptr, B, 384);             // kpre -> B
    dwconv_kernel<0><<<gDW, blk, 0, stream>>>(B, kv_dw, D);                  // k -> D
    sgemm<0><<<gGE, blk, 0, stream>>>(kv_w + (size_t)384 * 384, A, nullptr, B, 384); // vpre -> B
    dwconv_kernel<0><<<gDW, blk, 0, stream>>>(B, kv_dw + 384 * 9, A);        // v -> A

    rowsumsq_kernel<<<dim3(Bn * Cn), blk, 0, stream>>>(C, rq);
    rowsumsq_kernel<<<dim3(Bn * Cn), blk, 0, stream>>>(D, rk);

    qk_simple<<<dim3(CH / 6, HEADS_, Bn), blk, 0, stream>>>(C, D, attn);
    softmax_kernel<<<dim3(Bn * HEADS_ * CH), dim3(64), 0, stream>>>(attn, temp, rq, rk);
    pv_simple<<<dim3(Nn / 256, HEADS_, Bn), blk, 0, stream>>>(attn, A, B);   // aout -> B

    // x1 = x + proj(aout) -> d_out (FP32)
    sgemm<1><<<gGE, blk, 0, stream>>>(proj_w, B, x, outp, 384);

    // --- FFN branch ---
    ln_kernel<0><<<gLN, blk, 0, stream>>>(outp, n2_w, n2_b, A);              // xn2 -> A

    // h1a (hidden 0..383) -> B
    sgemm<0><<<gGE, blk, 0, stream>>>(ffn_in_w, A, nullptr, C, 384);
    dwconv_kernel<1><<<gDW, blk, 0, stream>>>(C, ffn_dw, B);
    sgemm<0><<<gGE, blk, 0, stream>>>(ffn_in_w + (size_t)768 * 384, A, nullptr, C, 384);
    dwconv_kernel<2><<<gDW, blk, 0, stream>>>(C, ffn_dw + (size_t)768 * 9, B);
    // h1b (hidden 384..767) -> D
    sgemm<0><<<gGE, blk, 0, stream>>>(ffn_in_w + (size_t)384 * 384, A, nullptr, C, 384);
    dwconv_kernel<1><<<gDW, blk, 0, stream>>>(C, ffn_dw + (size_t)384 * 9, D);
    sgemm<0><<<gGE, blk, 0, stream>>>(ffn_in_w + (size_t)1152 * 384, A, nullptr, C, 384);
    dwconv_kernel<2><<<gDW, blk, 0, stream>>>(C, ffn_dw + (size_t)1152 * 9, D);

    // out = x1 + W2 @ [h1a; h1b]  (in-place fp32 residual in d_out)
    sgemm_ffn<<<gGE, blk, 0, stream>>>(ffn_out_w, B, D, outp);
}

// Round 6
// 3012.480 us; speedup vs baseline: 6.5175x; 6.5175x over previous
//
#include <hip/hip_runtime.h>
#include <hip/hip_bf16.h>

using u16 = unsigned short;
using u32 = unsigned int;

constexpr int Bn = 4;
constexpr int Cn = 384;
constexpr int Hn = 128;
constexpr int Wn = 128;
constexpr int Nn = Hn * Wn;        // 16384
constexpr int HEADS_ = 8;
constexpr int CH = Cn / HEADS_;    // 48

typedef __attribute__((ext_vector_type(8))) short bf16x8;
typedef __attribute__((ext_vector_type(4))) float f32x4;

// ---- bf16 <-> f32 helpers (RNE, matches np/jax cast) ----
__device__ __forceinline__ float bf2f(u16 u) {
    u32 w = ((u32)u) << 16;
    return __builtin_bit_cast(float, w);
}
__device__ __forceinline__ u16 f2bf(float f) {
    u32 x = __builtin_bit_cast(u32, f);
    u32 r = (x + 0x7FFFu + ((x >> 16) & 1u)) >> 16;   // round-nearest-even
    return (u16)r;
}
__device__ __forceinline__ u32 pk2(float a, float b) {
    return (u32)f2bf(a) | (((u32)f2bf(b)) << 16);
}

// ============ LayerNorm: NCHW fp32 in -> NHWC bf16 out ============
// block 256 = 4 waves; 64 pixels per block; wave w covers c in [96w,96w+96)
__global__ __launch_bounds__(256) void ln_nhwc(
    const float* __restrict__ x, const float* __restrict__ w,
    const float* __restrict__ bias, u16* __restrict__ out)
{
    __shared__ float psum[4][64], pss[4][64], muA[64], rsA[64];
    __shared__ u16 Tl[64][386];          // stride 386 -> bank-conflict-free writes
    int t = threadIdx.x, p = t & 63, wv = t >> 6;
    int P0 = blockIdx.x * 64;            // global pixel base (b*Nn+n)
    int b = P0 >> 14;
    int n0 = P0 & (Nn - 1);
    const float* xb = x + (size_t)b * Cn * Nn + n0 + p;
    float s = 0.f, ss = 0.f;
    for (int cc = 0; cc < 96; ++cc) {
        int c = wv * 96 + cc;
        float v = xb[(size_t)c * Nn];
        s += v; ss += v * v;
    }
    psum[wv][p] = s; pss[wv][p] = ss;
    __syncthreads();
    if (t < 64) {
        float su = psum[0][t] + psum[1][t] + psum[2][t] + psum[3][t];
        float sq = pss[0][t] + pss[1][t] + pss[2][t] + pss[3][t];
        float mu = su * (1.f / 384.f);
        float var = sq * (1.f / 384.f) - mu * mu;
        muA[t] = mu; rsA[t] = rsqrtf(var + 1e-5f);
    }
    __syncthreads();
    float mu = muA[p], rs = rsA[p];
    for (int cc = 0; cc < 96; ++cc) {
        int c = wv * 96 + cc;
        float v = xb[(size_t)c * Nn];
        Tl[p][c] = f2bf((v - mu) * rs * w[c] + bias[c]);
    }
    __syncthreads();
    u16* ob = out + (size_t)P0 * 384;
    #pragma unroll 4
    for (int i = 0; i < 48; ++i) {
        int e = t + i * 256;             // 0..12287 (64 rows x 192 dwords)
        int pr = e / 192, cd = e % 192;
        u32 v = *(const u32*)&Tl[pr][cd * 2];
        *(u32*)(ob + (size_t)pr * 384 + cd * 2) = v;
    }
}

// ============ depthwise 3x3 SAME, NHWC bf16, lanes along c ============
__device__ __forceinline__ float gelu_exact(float v) {
    return 0.5f * v * (1.f + erff(v * 0.7071067811865475f));
}

// MODE 0: out = dw(in); 1: out = gelu(dw(in)); 2: out *= dw(in)
template<int MODE>
__global__ __launch_bounds__(256) void dwconv_nhwc(
    const u16* __restrict__ in, const float* __restrict__ wdw,
    u16* out, int C)
{
    int c = blockIdx.x * 64 + threadIdx.x;    // block (64,4)
    int n = blockIdx.y * 4 + threadIdx.y;
    int b = blockIdx.z;
    int h = n >> 7, w = n & (Wn - 1);
    const u16* base = in + (size_t)b * Nn * C;
    float wr[9];
    #pragma unroll
    for (int j = 0; j < 9; ++j) wr[j] = wdw[c * 9 + j];
    float acc = 0.f;
    #pragma unroll
    for (int ky = 0; ky < 3; ++ky) {
        int hh = h + ky - 1;
        if (hh < 0 || hh >= Hn) continue;
        #pragma unroll
        for (int kx = 0; kx < 3; ++kx) {
            int ww = w + kx - 1;
            if (ww < 0 || ww >= Wn) continue;
            acc = fmaf(bf2f(base[(size_t)(hh * Wn + ww) * C + c]), wr[ky * 3 + kx], acc);
        }
    }
    size_t oidx = ((size_t)b * Nn + n) * C + c;
    if (MODE == 0)      out[oidx] = f2bf(acc);
    else if (MODE == 1) out[oidx] = f2bf(gelu_exact(acc));
    else                out[oidx] = f2bf(bf2f(out[oidx]) * acc);
}

// ============ MFMA GEMM: Out[b,n,o] = sum_c X[b,n,c] * W[o,c] ============
// X: NHWC bf16, row stride 384 (X1 = second half for K=768).
// W: fp32 [O][WS] row-major, converted to bf16 in staging.
// RESMODE 0: bf16 NHWC out (stride O). RESMODE 2: fp32 NCHW out + fp32 NCHW residual.
// block 256 = 4 waves (2n x 2o); tile 128n x 64o; BK=32.
template<int RESMODE>
__global__ __launch_bounds__(256) void gemm_mfma(
    const float* __restrict__ W, int WS,
    const u16* __restrict__ X0, const u16* __restrict__ X1,
    int K, int O,
    u16* outh, float* outf, const float* res)
{
    __shared__ u16 Xs[128][40];
    __shared__ u16 Ws[64][40];
    __shared__ float Lt[(RESMODE == 2) ? 128 * 33 : 1];
    int t = threadIdx.x;
    int lane = t & 63, wv = t >> 6;
    int wn = wv >> 1, wo = wv & 1;
    int l16 = lane & 15, lq = lane >> 4;
    int oB = blockIdx.x * 64;
    int nB = blockIdx.y * 128;
    int b = blockIdx.z;
    const size_t xoff = (size_t)(b * Nn + nB) * 384;

    f32x4 acc[4][2];
    #pragma unroll
    for (int i = 0; i < 4; ++i)
        #pragma unroll
        for (int j = 0; j < 2; ++j)
            acc[i][j] = (f32x4){0.f, 0.f, 0.f, 0.f};

    int srow = t >> 1, shalf = t & 1;     // X staging map
    int so = t >> 2, sq = t & 3;          // W staging map

    for (int k0 = 0; k0 < K; k0 += 32) {
        const u16* Xc = X0;
        int kk = k0;
        if (X1 != nullptr && k0 >= 384) { Xc = X1; kk = k0 - 384; }
        {   // stage X tile [128][32]
            const u16* src = Xc + xoff + (size_t)srow * 384 + kk + shalf * 16;
            uint4 u0 = *(const uint4*)(src);
            uint4 u1 = *(const uint4*)(src + 8);
            *(uint4*)&Xs[srow][shalf * 16] = u0;
            *(uint4*)&Xs[srow][shalf * 16 + 8] = u1;
        }
        {   // stage W tile [64][32] fp32 -> bf16
            const float* wsrc = W + (size_t)(oB + so) * WS + k0 + sq * 8;
            float4 f0 = *(const float4*)(wsrc);
            float4 f1 = *(const float4*)(wsrc + 4);
            uint4 pk;
            pk.x = pk2(f0.x, f0.y); pk.y = pk2(f0.z, f0.w);
            pk.z = pk2(f1.x, f1.y); pk.w = pk2(f1.z, f1.w);
            *(uint4*)&Ws[so][sq * 8] = pk;
        }
        __syncthreads();
        bf16x8 af[4], bfr[2];
        #pragma unroll
        for (int fn = 0; fn < 4; ++fn)
            af[fn] = *(const bf16x8*)&Xs[wn * 64 + fn * 16 + l16][lq * 8];
        #pragma unroll
        for (int fo = 0; fo < 2; ++fo)
            bfr[fo] = *(const bf16x8*)&Ws[wo * 32 + fo * 16 + l16][lq * 8];
        #pragma unroll
        for (int fn = 0; fn < 4; ++fn)
            #pragma unroll
            for (int fo = 0; fo < 2; ++fo)
                acc[fn][fo] = __builtin_amdgcn_mfma_f32_16x16x32_bf16(
                    af[fn], bfr[fo], acc[fn][fo], 0, 0, 0);
        __syncthreads();
    }

    if (RESMODE == 0) {
        #pragma unroll
        for (int fn = 0; fn < 4; ++fn)
            #pragma unroll
            for (int fo = 0; fo < 2; ++fo)
                #pragma unroll
                for (int r = 0; r < 4; ++r) {
                    int n = nB + wn * 64 + fn * 16 + lq * 4 + r;
                    int o = oB + wo * 32 + fo * 16 + l16;
                    outh[((size_t)b * Nn + n) * O + o] = f2bf(acc[fn][fo][r]);
                }
    } else {
        // transpose 128n x 64o fp32 through LDS in 2 chunks of 32 o; NCHW out + residual
        for (int oc = 0; oc < 2; ++oc) {
            if (wo == oc) {
                #pragma unroll
                for (int fn = 0; fn < 4; ++fn)
                    #pragma unroll
                    for (int fo = 0; fo < 2; ++fo)
                        #pragma unroll
                        for (int r = 0; r < 4; ++r)
                            Lt[(wn * 64 + fn * 16 + lq * 4 + r) * 33 + fo * 16 + l16]
                                = acc[fn][fo][r];
            }
            __syncthreads();
            int o = t >> 3, seg = t & 7;
            int og = oB + oc * 32 + o;
            size_t bgl = ((size_t)b * O + og) * Nn + nB + seg * 16;
            #pragma unroll
            for (int i4 = 0; i4 < 4; ++i4) {
                int nl = seg * 16 + i4 * 4;
                float4 v;
                v.x = Lt[(nl + 0) * 33 + o];
                v.y = Lt[(nl + 1) * 33 + o];
                v.z = Lt[(nl + 2) * 33 + o];
                v.w = Lt[(nl + 3) * 33 + o];
                float4 rr = *(const float4*)(res + bgl + i4 * 4);
                v.x += rr.x; v.y += rr.y; v.z += rr.z; v.w += rr.w;
                *(float4*)(outf + bgl + i4 * 4) = v;
            }
            __syncthreads();
        }
    }
}

// ============ row sum-of-squares over n (NHWC) -> rsqrt factor ============
__global__ __launch_bounds__(256) void rowsumsq_nhwc(
    const u16* __restrict__ src, int C, float* __restrict__ rsq)
{
    __shared__ float red[4][64];
    int t = threadIdx.x;
    int c = blockIdx.x * 64 + (t & 63);
    int part = t >> 6;
    int b = blockIdx.y;
    float s = 0.f;
    const u16* p = src + (size_t)b * Nn * C + c;
    for (int n = part * 4096; n < (part + 1) * 4096; ++n) {
        float v = bf2f(p[(size_t)n * C]);
        s = fmaf(v, v, s);
    }
    red[part][t & 63] = s;
    __syncthreads();
    if (t < 64) {
        float tot = red[0][t] + red[1][t] + red[2][t] + red[3][t];
        rsq[b * Cn + blockIdx.x * 64 + t] = rsqrtf(tot + 1e-12f);
    }
}

__global__ void zero_kernel(float* p, int n) {
    int i = blockIdx.x * blockDim.x + threadIdx.x;
    if (i < n) p[i] = 0.f;
}

// ============ QK^T via MFMA: attn[c][d] += sum_n q[n][c]*k[n][d] ============
// grid (64 n-splits, 8 h, 4 b); block 256 = 4 waves, each wave 64 of the 256 n's.
__global__ __launch_bounds__(256) void qk_mfma(
    const u16* __restrict__ q, const u16* __restrict__ kv, float* __restrict__ attn)
{
    __shared__ u16 qT[48][264];
    __shared__ u16 kT[48][264];
    __shared__ float Lacc[48 * 48];
    int t = threadIdx.x, lane = t & 63, wv = t >> 6;
    int l16 = lane & 15, lq = lane >> 4;
    int n0 = blockIdx.x * 256;
    int h = blockIdx.y, b = blockIdx.z;
    int c0 = h * CH;
    #pragma unroll
    for (int i = 0; i < 9; ++i) Lacc[t + i * 256] = 0.f;
    for (int i = 0; i < 48; ++i) {
        int e = t + i * 256;               // 48*256
        int cc = e % 48, nn = e / 48;
        qT[cc][nn] = q [((size_t)(b * Nn) + n0 + nn) * 384 + c0 + cc];
        kT[cc][nn] = kv[((size_t)(b * Nn) + n0 + nn) * 768 + c0 + cc];
    }
    __syncthreads();
    f32x4 acc[3][3];
    #pragma unroll
    for (int i = 0; i < 3; ++i)
        #pragma unroll
        for (int j = 0; j < 3; ++j)
            acc[i][j] = (f32x4){0.f, 0.f, 0.f, 0.f};
    #pragma unroll
    for (int ks = 0; ks < 2; ++ks) {
        int kb = wv * 64 + ks * 32 + lq * 8;
        bf16x8 aq[3], bk[3];
        #pragma unroll
        for (int f = 0; f < 3; ++f) {
            aq[f] = *(const bf16x8*)&qT[f * 16 + l16][kb];
            bk[f] = *(const bf16x8*)&kT[f * 16 + l16][kb];
        }
        #pragma unroll
        for (int i = 0; i < 3; ++i)
            #pragma unroll
            for (int j = 0; j < 3; ++j)
                acc[i][j] = __builtin_amdgcn_mfma_f32_16x16x32_bf16(
                    aq[i], bk[j], acc[i][j], 0, 0, 0);
    }
    #pragma unroll
    for (int i = 0; i < 3; ++i)
        #pragma unroll
        for (int j = 0; j < 3; ++j)
            #pragma unroll
            for (int r = 0; r < 4; ++r) {
                int cq = i * 16 + lq * 4 + r;
                int dk = j * 16 + l16;
                atomicAdd(&Lacc[cq * 48 + dk], acc[i][j][r]);
            }
    __syncthreads();
    float* ap = attn + (size_t)(b * HEADS_ + h) * CH * CH;
    #pragma unroll
    for (int i = 0; i < 9; ++i) {
        int e = t + i * 256;
        atomicAdd(&ap[e], Lacc[e]);
    }
}

// ============ softmax over d (48) with temp & L2-norm factors ============
__global__ void softmax_kernel(float* __restrict__ attn,
                               const float* __restrict__ temp,
                               const float* __restrict__ rq,
                               const float* __restrict__ rk)
{
    int row = blockIdx.x;                   // B*H*CH rows
    int c = row % CH;
    int bh = row / CH;
    int h = bh % HEADS_, b = bh / HEADS_;
    float* p = attn + (size_t)row * CH;
    int d = threadIdx.x;                    // 64 lanes
    float tv = temp[h] * rq[b * Cn + h * CH + c];
    float raw = 0.f, val = -3.402823466e38f;
    if (d < CH) { raw = p[d] * tv * rk[b * Cn + h * CH + d]; val = raw; }
    #pragma unroll
    for (int off = 32; off > 0; off >>= 1) val = fmaxf(val, __shfl_xor(val, off));
    float e = (d < CH) ? __expf(raw - val) : 0.f;
    float s = e;
    #pragma unroll
    for (int off = 32; off > 0; off >>= 1) s += __shfl_xor(s, off);
    if (d < CH) p[d] = e / s;
}

// ============ PV via MFMA: aout[n][h*48+c] = sum_d P[c][d] * v[n][d] ============
// grid (8 h, 64 n-blocks, 4 b); block 256 = 4 waves x 64 n.
__global__ __launch_bounds__(256) void pv_mfma(
    const float* __restrict__ attn, const u16* __restrict__ kv, u16* __restrict__ out)
{
    __shared__ u16 Pl[48][72];              // [c][d], d padded to 64
    int t = threadIdx.x, lane = t & 63, wv = t >> 6;
    int l16 = lane & 15, lq = lane >> 4;
    int h = blockIdx.x, nb = blockIdx.y, b = blockIdx.z;
    int n0 = nb * 256;
    const float* ap = attn + (size_t)(b * HEADS_ + h) * CH * CH;
    #pragma unroll
    for (int i = 0; i < 12; ++i) {
        int e = t + i * 256;                // 48*64
        int c = e >> 6, d = e & 63;
        Pl[c][d] = (d < 48) ? f2bf(ap[c * 48 + d]) : (u16)0;
    }
    __syncthreads();
    f32x4 acc[4][3];
    #pragma unroll
    for (int i = 0; i < 4; ++i)
        #pragma unroll
        for (int j = 0; j < 3; ++j)
            acc[i][j] = (f32x4){0.f, 0.f, 0.f, 0.f};
    const u16* vb = kv + ((size_t)(b * Nn) + n0 + wv * 64) * 768 + 384 + h * CH;
    #pragma unroll
    for (int ks = 0; ks < 2; ++ks) {
        bf16x8 av[4], bp[3];
        #pragma unroll
        for (int fn = 0; fn < 4; ++fn)
            av[fn] = *(const bf16x8*)(vb + (size_t)(fn * 16 + l16) * 768 + ks * 32 + lq * 8);
        #pragma unroll
        for (int fo = 0; fo < 3; ++fo)
            bp[fo] = *(const bf16x8*)&Pl[fo * 16 + l16][ks * 32 + lq * 8];
        #pragma unroll
        for (int fn = 0; fn < 4; ++fn)
            #pragma unroll
            for (int fo = 0; fo < 3; ++fo)
                acc[fn][fo] = __builtin_amdgcn_mfma_f32_16x16x32_bf16(
                    av[fn], bp[fo], acc[fn][fo], 0, 0, 0);
    }
    #pragma unroll
    for (int fn = 0; fn < 4; ++fn)
        #pragma unroll
        for (int fo = 0; fo < 3; ++fo)
            #pragma unroll
            for (int r = 0; r < 4; ++r) {
                int n = n0 + wv * 64 + fn * 16 + lq * 4 + r;
                int c = fo * 16 + l16;
                out[((size_t)b * Nn + n) * 384 + h * CH + c] = f2bf(acc[fn][fo][r]);
            }
}

extern "C" void kernel_launch(void* const* d_in, const int* in_sizes, int n_in,
                              void* d_out, int out_size, void* d_ws, size_t ws_size,
                              hipStream_t stream) {
    const float* x        = (const float*)d_in[0];
    const float* y        = (const float*)d_in[1];
    const float* n1_w     = (const float*)d_in[2];
    const float* n1_b     = (const float*)d_in[3];
    const float* n1y_w    = (const float*)d_in[4];
    const float* n1y_b    = (const float*)d_in[5];
    const float* q_w      = (const float*)d_in[6];
    const float* q_dw     = (const float*)d_in[7];
    const float* kv_w     = (const float*)d_in[8];
    const float* kv_dw    = (const float*)d_in[9];
    const float* temp     = (const float*)d_in[10];
    const float* proj_w   = (const float*)d_in[11];
    const float* n2_w     = (const float*)d_in[12];
    const float* n2_b     = (const float*)d_in[13];
    const float* ffn_in_w = (const float*)d_in[14];
    const float* ffn_dw   = (const float*)d_in[15];
    const float* ffn_out_w= (const float*)d_in[16];
    float* outp = (float*)d_out;             // fp32 NCHW output

    const size_t S = (size_t)Bn * Cn * Nn;   // elems of one [b][n][384] tensor

    u16* R0 = (u16*)d_ws;                    // 4 bf16 NHWC regions, 48MB each
    u16* R1 = R0 + S;
    u16* R2 = R1 + S;
    u16* R3 = R2 + S;
    float* rq   = (float*)(R3 + S);
    float* rk   = rq + Bn * Cn;
    float* attn = rk + Bn * Cn;              // Bn*HEADS_*CH*CH = 92160 floats

    dim3 blk(256);
    dim3 gLN(Bn * Nn / 64);
    dim3 bDW(64, 4);

    // --- attention branch ---
    ln_nhwc<<<gLN, blk, 0, stream>>>(y, n1y_w, n1y_b, R3);                        // yn -> R3
    gemm_mfma<0><<<dim3(12, 128, Bn), blk, 0, stream>>>(                          // kvpre -> R0uR1
        kv_w, 384, R3, nullptr, 384, 768, R0, nullptr, nullptr);
    dwconv_nhwc<0><<<dim3(12, Nn / 4, Bn), bDW, 0, stream>>>(R0, kv_dw, R2, 768); // kv -> R2uR3

    ln_nhwc<<<gLN, blk, 0, stream>>>(x, n1_w, n1_b, R0);                          // xn -> R0
    gemm_mfma<0><<<dim3(6, 128, Bn), blk, 0, stream>>>(                           // qpre -> R1
        q_w, 384, R0, nullptr, 384, 384, R1, nullptr, nullptr);
    dwconv_nhwc<0><<<dim3(6, Nn / 4, Bn), bDW, 0, stream>>>(R1, q_dw, R0, 384);   // q -> R0

    rowsumsq_nhwc<<<dim3(6, Bn), blk, 0, stream>>>(R0, 384, rq);
    rowsumsq_nhwc<<<dim3(6, Bn), blk, 0, stream>>>(R2, 768, rk);

    zero_kernel<<<dim3(Bn * HEADS_ * CH * CH / 256), blk, 0, stream>>>(attn, Bn * HEADS_ * CH * CH);
    qk_mfma<<<dim3(64, HEADS_, Bn), blk, 0, stream>>>(R0, R2, attn);
    softmax_kernel<<<dim3(Bn * HEADS_ * CH), dim3(64), 0, stream>>>(attn, temp, rq, rk);
    pv_mfma<<<dim3(HEADS_, 64, Bn), blk, 0, stream>>>(attn, R2, R1);              // aout -> R1

    // x1 = x + proj(aout) -> d_out (fp32 NCHW)
    gemm_mfma<2><<<dim3(6, 128, Bn), blk, 0, stream>>>(
        proj_w, 384, R1, nullptr, 384, 384, nullptr, outp, x);

    // --- FFN branch ---
    ln_nhwc<<<gLN, blk, 0, stream>>>(outp, n2_w, n2_b, R0);                       // xn2 -> R0

    // g_lo -> R2 : gelu(dw(hx[0..383])) * dw(hx[768..1151])
    gemm_mfma<0><<<dim3(6, 128, Bn), blk, 0, stream>>>(
        ffn_in_w, 384, R0, nullptr, 384, 384, R1, nullptr, nullptr);
    dwconv_nhwc<1><<<dim3(6, Nn / 4, Bn), bDW, 0, stream>>>(R1, ffn_dw, R2, 384);
    gemm_mfma<0><<<dim3(6, 128, Bn), blk, 0, stream>>>(
        ffn_in_w + (size_t)768 * 384, 384, R0, nullptr, 384, 384, R1, nullptr, nullptr);
    dwconv_nhwc<2><<<dim3(6, Nn / 4, Bn), bDW, 0, stream>>>(R1, ffn_dw + 768 * 9, R2, 384);
    // g_hi -> R3 : gelu(dw(hx[384..767])) * dw(hx[1152..1535])
    gemm_mfma<0><<<dim3(6, 128, Bn), blk, 0, stream>>>(
        ffn_in_w + (size_t)384 * 384, 384, R0, nullptr, 384, 384, R1, nullptr, nullptr);
    dwconv_nhwc<1><<<dim3(6, Nn / 4, Bn), bDW, 0, stream>>>(R1, ffn_dw + 384 * 9, R3, 384);
    gemm_mfma<0><<<dim3(6, 128, Bn), blk, 0, stream>>>(
        ffn_in_w + (size_t)1152 * 384, 384, R0, nullptr, 384, 384, R1, nullptr, nullptr);
    dwconv_nhwc<2><<<dim3(6, Nn / 4, Bn), bDW, 0, stream>>>(R1, ffn_dw + 1152 * 9, R3, 384);

    // out = x1 + W2 @ [g_lo; g_hi]  (in-place fp32 NCHW residual in d_out)
    gemm_mfma<2><<<dim3(6, 128, Bn), blk, 0, stream>>>(
        ffn_out_w, 768, R2, R3, 768, 384, nullptr, outp, outp);
}

// Round 7
// 2331.521 us; speedup vs baseline: 8.4210x; 1.2921x over previous
//
#include <hip/hip_runtime.h>
#include <hip/hip_bf16.h>

using u16 = unsigned short;
using u32 = unsigned int;

constexpr int Bn = 4;
constexpr int Cn = 384;
constexpr int Hn = 128;
constexpr int Wn = 128;
constexpr int Nn = Hn * Wn;        // 16384
constexpr int HEADS_ = 8;
constexpr int CH = Cn / HEADS_;    // 48

typedef __attribute__((ext_vector_type(8))) short bf16x8;
typedef __attribute__((ext_vector_type(4))) float f32x4;

// ---- bf16 <-> f32 helpers (RNE, matches np/jax cast) ----
__device__ __forceinline__ float bf2f(u16 u) {
    u32 w = ((u32)u) << 16;
    return __builtin_bit_cast(float, w);
}
__device__ __forceinline__ u16 f2bf(float f) {
    u32 x = __builtin_bit_cast(u32, f);
    u32 r = (x + 0x7FFFu + ((x >> 16) & 1u)) >> 16;   // round-nearest-even
    return (u16)r;
}
__device__ __forceinline__ u32 pk2(float a, float b) {
    return (u32)f2bf(a) | (((u32)f2bf(b)) << 16);
}

// ============ LayerNorm: NCHW fp32 in -> NHWC bf16 out ============
// block 256 = 4 waves; 64 pixels per block; wave w covers c in [96w,96w+96)
__global__ __launch_bounds__(256) void ln_nhwc(
    const float* __restrict__ x, const float* __restrict__ w,
    const float* __restrict__ bias, u16* __restrict__ out)
{
    __shared__ float psum[4][64], pss[4][64], muA[64], rsA[64];
    __shared__ u16 Tl[64][386];          // stride 386 -> bank-conflict-free writes
    int t = threadIdx.x, p = t & 63, wv = t >> 6;
    int P0 = blockIdx.x * 64;            // global pixel base (b*Nn+n)
    int b = P0 >> 14;
    int n0 = P0 & (Nn - 1);
    const float* xb = x + (size_t)b * Cn * Nn + n0 + p;
    float s = 0.f, ss = 0.f;
    for (int cc = 0; cc < 96; ++cc) {
        int c = wv * 96 + cc;
        float v = xb[(size_t)c * Nn];
        s += v; ss += v * v;
    }
    psum[wv][p] = s; pss[wv][p] = ss;
    __syncthreads();
    if (t < 64) {
        float su = psum[0][t] + psum[1][t] + psum[2][t] + psum[3][t];
        float sq = pss[0][t] + pss[1][t] + pss[2][t] + pss[3][t];
        float mu = su * (1.f / 384.f);
        float var = sq * (1.f / 384.f) - mu * mu;
        muA[t] = mu; rsA[t] = rsqrtf(var + 1e-5f);
    }
    __syncthreads();
    float mu = muA[p], rs = rsA[p];
    for (int cc = 0; cc < 96; ++cc) {
        int c = wv * 96 + cc;
        float v = xb[(size_t)c * Nn];
        Tl[p][c] = f2bf((v - mu) * rs * w[c] + bias[c]);
    }
    __syncthreads();
    u16* ob = out + (size_t)P0 * 384;
    #pragma unroll 4
    for (int i = 0; i < 48; ++i) {
        int e = t + i * 256;             // 0..12287 (64 rows x 192 dwords)
        int pr = e / 192, cd = e % 192;
        u32 v = *(const u32*)&Tl[pr][cd * 2];
        *(u32*)(ob + (size_t)pr * 384 + cd * 2) = v;
    }
}

// ============ depthwise 3x3 SAME, NHWC bf16, lanes along c ============
__device__ __forceinline__ float gelu_exact(float v) {
    return 0.5f * v * (1.f + erff(v * 0.7071067811865475f));
}

// MODE 0: out = dw(in); 1: out = gelu(dw(in)); 2: out *= dw(in)
template<int MODE>
__global__ __launch_bounds__(256) void dwconv_nhwc(
    const u16* __restrict__ in, const float* __restrict__ wdw,
    u16* out, int C)
{
    int c = blockIdx.x * 64 + threadIdx.x;    // block (64,4)
    int n = blockIdx.y * 4 + threadIdx.y;
    int b = blockIdx.z;
    int h = n >> 7, w = n & (Wn - 1);
    const u16* base = in + (size_t)b * Nn * C;
    float wr[9];
    #pragma unroll
    for (int j = 0; j < 9; ++j) wr[j] = wdw[c * 9 + j];
    float acc = 0.f;
    #pragma unroll
    for (int ky = 0; ky < 3; ++ky) {
        int hh = h + ky - 1;
        if (hh < 0 || hh >= Hn) continue;
        #pragma unroll
        for (int kx = 0; kx < 3; ++kx) {
            int ww = w + kx - 1;
            if (ww < 0 || ww >= Wn) continue;
            acc = fmaf(bf2f(base[(size_t)(hh * Wn + ww) * C + c]), wr[ky * 3 + kx], acc);
        }
    }
    size_t oidx = ((size_t)b * Nn + n) * C + c;
    if (MODE == 0)      out[oidx] = f2bf(acc);
    else if (MODE == 1) out[oidx] = f2bf(gelu_exact(acc));
    else                out[oidx] = f2bf(bf2f(out[oidx]) * acc);
}

// ============ MFMA GEMM: Out[b,n,o] = sum_c X[b,n,c] * W[o,c] ============
// X: NHWC bf16, row stride 384 (X1 = second half for K=768).
// W: fp32 [O][WS] row-major, converted to bf16 in staging.
// RESMODE 0: bf16 NHWC out (stride O). RESMODE 2: fp32 NCHW out + fp32 NCHW residual.
// block 256 = 4 waves (2n x 2o); tile 128n x 64o; BK=32.
template<int RESMODE>
__global__ __launch_bounds__(256) void gemm_mfma(
    const float* __restrict__ W, int WS,
    const u16* __restrict__ X0, const u16* __restrict__ X1,
    int K, int O,
    u16* outh, float* outf, const float* res)
{
    __shared__ u16 Xs[128][40];
    __shared__ u16 Ws[64][40];
    __shared__ float Lt[(RESMODE == 2) ? 128 * 33 : 1];
    int t = threadIdx.x;
    int lane = t & 63, wv = t >> 6;
    int wn = wv >> 1, wo = wv & 1;
    int l16 = lane & 15, lq = lane >> 4;
    int oB = blockIdx.x * 64;
    int nB = blockIdx.y * 128;
    int b = blockIdx.z;
    const size_t xoff = (size_t)(b * Nn + nB) * 384;

    f32x4 acc[4][2];
    #pragma unroll
    for (int i = 0; i < 4; ++i)
        #pragma unroll
        for (int j = 0; j < 2; ++j)
            acc[i][j] = (f32x4){0.f, 0.f, 0.f, 0.f};

    int srow = t >> 1, shalf = t & 1;     // X staging map
    int so = t >> 2, sq = t & 3;          // W staging map

    for (int k0 = 0; k0 < K; k0 += 32) {
        const u16* Xc = X0;
        int kk = k0;
        if (X1 != nullptr && k0 >= 384) { Xc = X1; kk = k0 - 384; }
        {   // stage X tile [128][32]
            const u16* src = Xc + xoff + (size_t)srow * 384 + kk + shalf * 16;
            uint4 u0 = *(const uint4*)(src);
            uint4 u1 = *(const uint4*)(src + 8);
            *(uint4*)&Xs[srow][shalf * 16] = u0;
            *(uint4*)&Xs[srow][shalf * 16 + 8] = u1;
        }
        {   // stage W tile [64][32] fp32 -> bf16
            const float* wsrc = W + (size_t)(oB + so) * WS + k0 + sq * 8;
            float4 f0 = *(const float4*)(wsrc);
            float4 f1 = *(const float4*)(wsrc + 4);
            uint4 pk;
            pk.x = pk2(f0.x, f0.y); pk.y = pk2(f0.z, f0.w);
            pk.z = pk2(f1.x, f1.y); pk.w = pk2(f1.z, f1.w);
            *(uint4*)&Ws[so][sq * 8] = pk;
        }
        __syncthreads();
        bf16x8 af[4], bfr[2];
        #pragma unroll
        for (int fn = 0; fn < 4; ++fn)
            af[fn] = *(const bf16x8*)&Xs[wn * 64 + fn * 16 + l16][lq * 8];
        #pragma unroll
        for (int fo = 0; fo < 2; ++fo)
            bfr[fo] = *(const bf16x8*)&Ws[wo * 32 + fo * 16 + l16][lq * 8];
        #pragma unroll
        for (int fn = 0; fn < 4; ++fn)
            #pragma unroll
            for (int fo = 0; fo < 2; ++fo)
                acc[fn][fo] = __builtin_amdgcn_mfma_f32_16x16x32_bf16(
                    af[fn], bfr[fo], acc[fn][fo], 0, 0, 0);
        __syncthreads();
    }

    if (RESMODE == 0) {
        #pragma unroll
        for (int fn = 0; fn < 4; ++fn)
            #pragma unroll
            for (int fo = 0; fo < 2; ++fo)
                #pragma unroll
                for (int r = 0; r < 4; ++r) {
                    int n = nB + wn * 64 + fn * 16 + lq * 4 + r;
                    int o = oB + wo * 32 + fo * 16 + l16;
                    outh[((size_t)b * Nn + n) * O + o] = f2bf(acc[fn][fo][r]);
                }
    } else {
        // transpose 128n x 64o fp32 through LDS in 2 chunks of 32 o; NCHW out + residual
        for (int oc = 0; oc < 2; ++oc) {
            if (wo == oc) {
                #pragma unroll
                for (int fn = 0; fn < 4; ++fn)
                    #pragma unroll
                    for (int fo = 0; fo < 2; ++fo)
                        #pragma unroll
                        for (int r = 0; r < 4; ++r)
                            Lt[(wn * 64 + fn * 16 + lq * 4 + r) * 33 + fo * 16 + l16]
                                = acc[fn][fo][r];
            }
            __syncthreads();
            int o = t >> 3, seg = t & 7;
            int og = oB + oc * 32 + o;
            size_t bgl = ((size_t)b * O + og) * Nn + nB + seg * 16;
            #pragma unroll
            for (int i4 = 0; i4 < 4; ++i4) {
                int nl = seg * 16 + i4 * 4;
                float4 v;
                v.x = Lt[(nl + 0) * 33 + o];
                v.y = Lt[(nl + 1) * 33 + o];
                v.z = Lt[(nl + 2) * 33 + o];
                v.w = Lt[(nl + 3) * 33 + o];
                float4 rr = *(const float4*)(res + bgl + i4 * 4);
                v.x += rr.x; v.y += rr.y; v.z += rr.z; v.w += rr.w;
                *(float4*)(outf + bgl + i4 * 4) = v;
            }
            __syncthreads();
        }
    }
}

// ============ per-channel sum of squares (NHWC, coalesced, atomic accumulate) ====
// block 384 thr = 6 waves; thread t owns 4 consecutive channels (cq=t%96),
// row-group rg=t/96 covers pixel n0+4i+rg. One atomicAdd per channel per block.
__global__ __launch_bounds__(384) void sumsq_nhwc(
    const u16* __restrict__ src, int stride, float* __restrict__ acc)
{
    __shared__ float ls[96][4][4];          // [cq][rg][j]
    int t = threadIdx.x;
    int cq = t % 96, rg = t / 96;
    int b = blockIdx.y;
    int n0 = blockIdx.x * 64;
    const u16* p = src + ((size_t)b * Nn + n0) * stride + cq * 4;
    float s0 = 0.f, s1 = 0.f, s2 = 0.f, s3 = 0.f;
    #pragma unroll 4
    for (int i = 0; i < 16; ++i) {
        int n = i * 4 + rg;
        uint2 u = *(const uint2*)(p + (size_t)n * stride);
        float v0 = bf2f((u16)(u.x & 0xFFFF)), v1 = bf2f((u16)(u.x >> 16));
        float v2 = bf2f((u16)(u.y & 0xFFFF)), v3 = bf2f((u16)(u.y >> 16));
        s0 = fmaf(v0, v0, s0); s1 = fmaf(v1, v1, s1);
        s2 = fmaf(v2, v2, s2); s3 = fmaf(v3, v3, s3);
    }
    ls[cq][rg][0] = s0; ls[cq][rg][1] = s1; ls[cq][rg][2] = s2; ls[cq][rg][3] = s3;
    __syncthreads();
    if (t < 96) {
        #pragma unroll
        for (int j = 0; j < 4; ++j) {
            float tot = ls[t][0][j] + ls[t][1][j] + ls[t][2][j] + ls[t][3][j];
            atomicAdd(&acc[b * Cn + t * 4 + j], tot);
        }
    }
}

__global__ void zero_kernel(float* p, int n) {
    int i = blockIdx.x * blockDim.x + threadIdx.x;
    if (i < n) p[i] = 0.f;
}

// ============ QK^T via MFMA: attn[c][d] += sum_n q[n][c]*k[n][d] ============
// grid (64 n-splits, 8 h, 4 b); block 256 = 4 waves, each wave 64 of the 256 n's.
__global__ __launch_bounds__(256) void qk_mfma(
    const u16* __restrict__ q, const u16* __restrict__ kv, float* __restrict__ attn)
{
    __shared__ u16 qT[48][264];
    __shared__ u16 kT[48][264];
    __shared__ float Lacc[48 * 48];
    int t = threadIdx.x, lane = t & 63, wv = t >> 6;
    int l16 = lane & 15, lq = lane >> 4;
    int n0 = blockIdx.x * 256;
    int h = blockIdx.y, b = blockIdx.z;
    int c0 = h * CH;
    #pragma unroll
    for (int i = 0; i < 9; ++i) Lacc[t + i * 256] = 0.f;
    for (int i = 0; i < 48; ++i) {
        int e = t + i * 256;               // 48*256
        int cc = e % 48, nn = e / 48;
        qT[cc][nn] = q [((size_t)(b * Nn) + n0 + nn) * 384 + c0 + cc];
        kT[cc][nn] = kv[((size_t)(b * Nn) + n0 + nn) * 768 + c0 + cc];
    }
    __syncthreads();
    f32x4 acc[3][3];
    #pragma unroll
    for (int i = 0; i < 3; ++i)
        #pragma unroll
        for (int j = 0; j < 3; ++j)
            acc[i][j] = (f32x4){0.f, 0.f, 0.f, 0.f};
    #pragma unroll
    for (int ks = 0; ks < 2; ++ks) {
        int kb = wv * 64 + ks * 32 + lq * 8;
        bf16x8 aq[3], bk[3];
        #pragma unroll
        for (int f = 0; f < 3; ++f) {
            aq[f] = *(const bf16x8*)&qT[f * 16 + l16][kb];
            bk[f] = *(const bf16x8*)&kT[f * 16 + l16][kb];
        }
        #pragma unroll
        for (int i = 0; i < 3; ++i)
            #pragma unroll
            for (int j = 0; j < 3; ++j)
                acc[i][j] = __builtin_amdgcn_mfma_f32_16x16x32_bf16(
                    aq[i], bk[j], acc[i][j], 0, 0, 0);
    }
    #pragma unroll
    for (int i = 0; i < 3; ++i)
        #pragma unroll
        for (int j = 0; j < 3; ++j)
            #pragma unroll
            for (int r = 0; r < 4; ++r) {
                int cq = i * 16 + lq * 4 + r;
                int dk = j * 16 + l16;
                atomicAdd(&Lacc[cq * 48 + dk], acc[i][j][r]);
            }
    __syncthreads();
    float* ap = attn + (size_t)(b * HEADS_ + h) * CH * CH;
    #pragma unroll
    for (int i = 0; i < 9; ++i) {
        int e = t + i * 256;
        atomicAdd(&ap[e], Lacc[e]);
    }
}

// ============ softmax over d (48); rq/rk are raw sums, rsqrt applied here ============
__global__ void softmax_kernel(float* __restrict__ attn,
                               const float* __restrict__ temp,
                               const float* __restrict__ rq,
                               const float* __restrict__ rk)
{
    int row = blockIdx.x;                   // B*H*CH rows
    int c = row % CH;
    int bh = row / CH;
    int h = bh % HEADS_, b = bh / HEADS_;
    float* p = attn + (size_t)row * CH;
    int d = threadIdx.x;                    // 64 lanes
    float tv = temp[h] * rsqrtf(rq[b * Cn + h * CH + c] + 1e-12f);
    float raw = 0.f, val = -3.402823466e38f;
    if (d < CH) {
        float rkf = rsqrtf(rk[b * Cn + h * CH + d] + 1e-12f);
        raw = p[d] * tv * rkf; val = raw;
    }
    #pragma unroll
    for (int off = 32; off > 0; off >>= 1) val = fmaxf(val, __shfl_xor(val, off));
    float e = (d < CH) ? __expf(raw - val) : 0.f;
    float s = e;
    #pragma unroll
    for (int off = 32; off > 0; off >>= 1) s += __shfl_xor(s, off);
    if (d < CH) p[d] = e / s;
}

// ============ PV via MFMA: aout[n][h*48+c] = sum_d P[c][d] * v[n][d] ============
// grid (8 h, 64 n-blocks, 4 b); block 256 = 4 waves x 64 n.
__global__ __launch_bounds__(256) void pv_mfma(
    const float* __restrict__ attn, const u16* __restrict__ kv, u16* __restrict__ out)
{
    __shared__ u16 Pl[48][72];              // [c][d], d padded to 64
    int t = threadIdx.x, lane = t & 63, wv = t >> 6;
    int l16 = lane & 15, lq = lane >> 4;
    int h = blockIdx.x, nb = blockIdx.y, b = blockIdx.z;
    int n0 = nb * 256;
    const float* ap = attn + (size_t)(b * HEADS_ + h) * CH * CH;
    #pragma unroll
    for (int i = 0; i < 12; ++i) {
        int e = t + i * 256;                // 48*64
        int c = e >> 6, d = e & 63;
        Pl[c][d] = (d < 48) ? f2bf(ap[c * 48 + d]) : (u16)0;
    }
    __syncthreads();
    f32x4 acc[4][3];
    #pragma unroll
    for (int i = 0; i < 4; ++i)
        #pragma unroll
        for (int j = 0; j < 3; ++j)
            acc[i][j] = (f32x4){0.f, 0.f, 0.f, 0.f};
    const u16* vb = kv + ((size_t)(b * Nn) + n0 + wv * 64) * 768 + 384 + h * CH;
    #pragma unroll
    for (int ks = 0; ks < 2; ++ks) {
        bf16x8 av[4], bp[3];
        #pragma unroll
        for (int fn = 0; fn < 4; ++fn)
            av[fn] = *(const bf16x8*)(vb + (size_t)(fn * 16 + l16) * 768 + ks * 32 + lq * 8);
        #pragma unroll
        for (int fo = 0; fo < 3; ++fo)
            bp[fo] = *(const bf16x8*)&Pl[fo * 16 + l16][ks * 32 + lq * 8];
        #pragma unroll
        for (int fn = 0; fn < 4; ++fn)
            #pragma unroll
            for (int fo = 0; fo < 3; ++fo)
                acc[fn][fo] = __builtin_amdgcn_mfma_f32_16x16x32_bf16(
                    av[fn], bp[fo], acc[fn][fo], 0, 0, 0);
    }
    #pragma unroll
    for (int fn = 0; fn < 4; ++fn)
        #pragma unroll
        for (int fo = 0; fo < 3; ++fo)
            #pragma unroll
            for (int r = 0; r < 4; ++r) {
                int n = n0 + wv * 64 + fn * 16 + lq * 4 + r;
                int c = fo * 16 + l16;
                out[((size_t)b * Nn + n) * 384 + h * CH + c] = f2bf(acc[fn][fo][r]);
            }
}

extern "C" void kernel_launch(void* const* d_in, const int* in_sizes, int n_in,
                              void* d_out, int out_size, void* d_ws, size_t ws_size,
                              hipStream_t stream) {
    const float* x        = (const float*)d_in[0];
    const float* y        = (const float*)d_in[1];
    const float* n1_w     = (const float*)d_in[2];
    const float* n1_b     = (const float*)d_in[3];
    const float* n1y_w    = (const float*)d_in[4];
    const float* n1y_b    = (const float*)d_in[5];
    const float* q_w      = (const float*)d_in[6];
    const float* q_dw     = (const float*)d_in[7];
    const float* kv_w     = (const float*)d_in[8];
    const float* kv_dw    = (const float*)d_in[9];
    const float* temp     = (const float*)d_in[10];
    const float* proj_w   = (const float*)d_in[11];
    const float* n2_w     = (const float*)d_in[12];
    const float* n2_b     = (const float*)d_in[13];
    const float* ffn_in_w = (const float*)d_in[14];
    const float* ffn_dw   = (const float*)d_in[15];
    const float* ffn_out_w= (const float*)d_in[16];
    float* outp = (float*)d_out;             // fp32 NCHW output

    const size_t S = (size_t)Bn * Cn * Nn;   // elems of one [b][n][384] tensor

    u16* R0 = (u16*)d_ws;                    // 4 bf16 NHWC regions, 48MB each
    u16* R1 = R0 + S;
    u16* R2 = R1 + S;
    u16* R3 = R2 + S;
    float* rq   = (float*)(R3 + S);
    float* rk   = rq + Bn * Cn;
    float* attn = rk + Bn * Cn;              // Bn*HEADS_*CH*CH = 92160 floats

    dim3 blk(256);
    dim3 gLN(Bn * Nn / 64);
    dim3 bDW(64, 4);

    // zero rq ∪ rk ∪ attn (contiguous: 3072 + 92160 = 95232 floats)
    zero_kernel<<<dim3(95232 / 256), blk, 0, stream>>>(rq, 95232);

    // --- attention branch ---
    ln_nhwc<<<gLN, blk, 0, stream>>>(y, n1y_w, n1y_b, R3);                        // yn -> R3
    gemm_mfma<0><<<dim3(12, 128, Bn), blk, 0, stream>>>(                          // kvpre -> R0uR1
        kv_w, 384, R3, nullptr, 384, 768, R0, nullptr, nullptr);
    dwconv_nhwc<0><<<dim3(12, Nn / 4, Bn), bDW, 0, stream>>>(R0, kv_dw, R2, 768); // kv -> R2uR3

    ln_nhwc<<<gLN, blk, 0, stream>>>(x, n1_w, n1_b, R0);                          // xn -> R0
    gemm_mfma<0><<<dim3(6, 128, Bn), blk, 0, stream>>>(                           // qpre -> R1
        q_w, 384, R0, nullptr, 384, 384, R1, nullptr, nullptr);
    dwconv_nhwc<0><<<dim3(6, Nn / 4, Bn), bDW, 0, stream>>>(R1, q_dw, R0, 384);   // q -> R0

    sumsq_nhwc<<<dim3(Nn / 64, Bn), dim3(384), 0, stream>>>(R0, 384, rq);         // q sums
    sumsq_nhwc<<<dim3(Nn / 64, Bn), dim3(384), 0, stream>>>(R2, 768, rk);         // k sums

    qk_mfma<<<dim3(64, HEADS_, Bn), blk, 0, stream>>>(R0, R2, attn);
    softmax_kernel<<<dim3(Bn * HEADS_ * CH), dim3(64), 0, stream>>>(attn, temp, rq, rk);
    pv_mfma<<<dim3(HEADS_, 64, Bn), blk, 0, stream>>>(attn, R2, R1);              // aout -> R1

    // x1 = x + proj(aout) -> d_out (fp32 NCHW)
    gemm_mfma<2><<<dim3(6, 128, Bn), blk, 0, stream>>>(
        proj_w, 384, R1, nullptr, 384, 384, nullptr, outp, x);

    // --- FFN branch ---
    ln_nhwc<<<gLN, blk, 0, stream>>>(outp, n2_w, n2_b, R0);                       // xn2 -> R0

    // g_lo -> R2 : gelu(dw(hx[0..383])) * dw(hx[768..1151])
    gemm_mfma<0><<<dim3(6, 128, Bn), blk, 0, stream>>>(
        ffn_in_w, 384, R0, nullptr, 384, 384, R1, nullptr, nullptr);
    dwconv_nhwc<1><<<dim3(6, Nn / 4, Bn), bDW, 0, stream>>>(R1, ffn_dw, R2, 384);
    gemm_mfma<0><<<dim3(6, 128, Bn), blk, 0, stream>>>(
        ffn_in_w + (size_t)768 * 384, 384, R0, nullptr, 384, 384, R1, nullptr, nullptr);
    dwconv_nhwc<2><<<dim3(6, Nn / 4, Bn), bDW, 0, stream>>>(R1, ffn_dw + 768 * 9, R2, 384);
    // g_hi -> R3 : gelu(dw(hx[384..767])) * dw(hx[1152..1535])
    gemm_mfma<0><<<dim3(6, 128, Bn), blk, 0, stream>>>(
        ffn_in_w + (size_t)384 * 384, 384, R0, nullptr, 384, 384, R1, nullptr, nullptr);
    dwconv_nhwc<1><<<dim3(6, Nn / 4, Bn), bDW, 0, stream>>>(R1, ffn_dw + 384 * 9, R3, 384);
    gemm_mfma<0><<<dim3(6, 128, Bn), blk, 0, stream>>>(
        ffn_in_w + (size_t)1152 * 384, 384, R0, nullptr, 384, 384, R1, nullptr, nullptr);
    dwconv_nhwc<2><<<dim3(6, Nn / 4, Bn), bDW, 0, stream>>>(R1, ffn_dw + 1152 * 9, R3, 384);

    // out = x1 + W2 @ [g_lo; g_hi]  (in-place fp32 NCHW residual in d_out)
    gemm_mfma<2><<<dim3(6, 128, Bn), blk, 0, stream>>>(
        ffn_out_w, 768, R2, R3, 768, 384, nullptr, outp, outp);
}